// Round 8
// baseline (74.193 us; speedup 1.0000x reference)
//
#include <hip/hip_runtime.h>

// Output: (1, 9, 16, 9, 256, 256) f32 — out[d][c][a][y][x]
// Input:  (1, 16, 9, 256, 256)  f32 — in[c][a][y][x]
// t = (d-4)*(a-4); out[d][c][a][y][x] = in[c][a][y-t][x-t] if in-bounds else 0.
//
// Round-5 structure (scatter, RTILE=16, dwordx4 NT stores) + round 8:
// XCD-chunked block swizzle. Default dispatch round-robins consecutive ids
// across 8 XCDs, spreading the 16 blocks that share one (c,a) input slice
// over all XCDs -> every per-XCD L2 refetches ~the whole input (~300 MB of
// fabric reads). Swizzle so XCD x owns ca in [18x, 18x+18): slice fetched
// into exactly one L2, read traffic back to ~38 MB.

#define RTILE 16

typedef float vf4 __attribute__((ext_vector_type(4)));

template<int TR>
__device__ __forceinline__ void emit_plane(const float* __restrict__ lds_t,
                                           float* __restrict__ oplane,
                                           int g0, int t, int tq,
                                           int tx, int ty)
{
    for (int yb = ty; yb < RTILE; yb += 4) {          // wave-uniform row
        int y = g0 + yb + t;
        if (y < 0 || y >= 256) continue;
        const float* __restrict__ lrow = lds_t + yb * 256;
        float* __restrict__ orow = oplane + (long)y * 256;

        int m2 = tx - tq;                 // aligned chunk indices
        int m2c = m2 < 0 ? 0 : (m2 > 63 ? 63 : m2);
        vf4 B = *reinterpret_cast<const vf4*>(lrow + 4 * m2c);
        float w0, w1, w2, w3;
        if (TR == 0) {
            w0 = B.x; w1 = B.y; w2 = B.z; w3 = B.w;
        } else {
            int m1 = m2 - 1;
            int m1c = m1 < 0 ? 0 : (m1 > 63 ? 63 : m1);
            vf4 A = *reinterpret_cast<const vf4*>(lrow + 4 * m1c);
            float cc[8] = {A.x, A.y, A.z, A.w, B.x, B.y, B.z, B.w};
            w0 = cc[4 - TR]; w1 = cc[5 - TR];         // compile-time indices
            w2 = cc[6 - TR]; w3 = cc[7 - TR];
        }
        int x0 = 4 * tx;
        int lo = t, hi = 256 + t;                     // valid x: [t, 256+t)
        vf4 v;
        v.x = (x0 + 0 >= lo && x0 + 0 < hi) ? w0 : 0.f;
        v.y = (x0 + 1 >= lo && x0 + 1 < hi) ? w1 : 0.f;
        v.z = (x0 + 2 >= lo && x0 + 2 < hi) ? w2 : 0.f;
        v.w = (x0 + 3 >= lo && x0 + 3 < hi) ? w3 : 0.f;
        __builtin_nontemporal_store(v, reinterpret_cast<vf4*>(orow + x0));
    }
}

__global__ __launch_bounds__(256) void cost_volume_kernel(
    const float* __restrict__ in, float* __restrict__ out)
{
    __shared__ float lds_t[RTILE * 256];   // 16 KB -> 8 blocks/CU

    // ---- XCD-chunked bijective swizzle (2304 blocks, 2304 % 8 == 0) ----
    int orig = blockIdx.x;                  // dispatch order; XCD = orig % 8
    int swz  = (orig & 7) * 288 + (orig >> 3);   // XCD x gets swz in [288x, 288x+288)
    int ca = swz >> 4;                      // ca-major: same slice -> same XCD
    int bx = swz & 15;                      // y-tile within slice

    int c = ca / 9;
    int a = ca - c * 9;
    int a4 = a - 4;
    int g0 = bx * RTILE;                    // first input row of tile

    int tx = threadIdx.x;                   // 0..63
    int ty = threadIdx.y;                   // 0..3

    // ---- stage 16 input rows, no halo ----
    const float* __restrict__ slice = in + (long)ca * 65536;
    #pragma unroll
    for (int r0 = 0; r0 < RTILE; r0 += 4) {
        int r = r0 + ty;
        *reinterpret_cast<vf4*>(&lds_t[r * 256 + tx * 4]) =
            *reinterpret_cast<const vf4*>(slice + (long)(g0 + r) * 256 + tx * 4);
    }
    __syncthreads();

    // ---- scatter to 9 d-shifted planes ----
    #pragma unroll
    for (int d = 0; d < 9; ++d) {
        int t = (d - 4) * a4;
        float* __restrict__ oplane = out + ((long)(d * 16 + c) * 9 + a) * 65536L;
        int tq = t >> 2;                    // arithmetic shift = floor div
        switch (t & 3) {
        case 0: emit_plane<0>(lds_t, oplane, g0, t, tq, tx, ty); break;
        case 1: emit_plane<1>(lds_t, oplane, g0, t, tq, tx, ty); break;
        case 2: emit_plane<2>(lds_t, oplane, g0, t, tq, tx, ty); break;
        case 3: emit_plane<3>(lds_t, oplane, g0, t, tq, tx, ty); break;
        }

        // ---- distributed zero-fill: block bx fills zero-row bx (if any) ----
        int zn = t < 0 ? -t : t;            // 0..16 uncovered rows per plane
        int z0 = t > 0 ? 0 : 256 + t;
        if (zn && ty == (d & 3) && bx < zn) {
            float* __restrict__ orow = oplane + (long)(z0 + bx) * 256;
            vf4 z = {0.f, 0.f, 0.f, 0.f};
            __builtin_nontemporal_store(z, reinterpret_cast<vf4*>(orow + tx * 4));
        }
    }
}

extern "C" void kernel_launch(void* const* d_in, const int* in_sizes, int n_in,
                              void* d_out, int out_size, void* d_ws, size_t ws_size,
                              hipStream_t stream)
{
    const float* in = (const float*)d_in[0];
    float* out = (float*)d_out;

    dim3 block(64, 4, 1);     // 256 threads = 4 waves
    dim3 grid(2304, 1, 1);    // 1-D so the swizzle controls XCD placement
    cost_volume_kernel<<<grid, block, 0, stream>>>(in, out);
}

// Round 9
// 74.169 us; speedup vs baseline: 1.0003x; 1.0003x over previous
//
#include <hip/hip_runtime.h>

// Output: (1, 9, 16, 9, 256, 256) f32 — out[d][c][a][y][x]
// Input:  (1, 16, 9, 256, 256)  f32 — in[c][a][y][x]
// t = (d-4)*(a-4); out[d][c][a][y][x] = in[c][a][y-t][x-t] if in-bounds else 0.
//
// Round 9: one block = ONE (d,ca) output plane = one contiguous 256-KB
// write stream (vs 9 scattered 16-KB bursts per block in R5). 1296 blocks,
// all co-resident, no LDS (funnel-shift reads aligned global chunks,
// L2/L3-served), t block-uniform. NT dwordx4 stores.

typedef float vf4 __attribute__((ext_vector_type(4)));
typedef unsigned int uint;

template<int TR>
__device__ __forceinline__ void plane_loop(const float* __restrict__ slice,
                                           float* __restrict__ oplane,
                                           int t, int tx, int ty)
{
    int tq = t >> 2;                      // floor(t/4); t = 4*tq + TR
    int m2 = tx - tq;                     // aligned chunk index for this lane
    int m2c = m2 < 0 ? 0 : (m2 > 63 ? 63 : m2);
    int m1 = m2 - 1;
    int m1c = m1 < 0 ? 0 : (m1 > 63 ? 63 : m1);
    int x0 = 4 * tx;
    // per-lane CONSTANT element masks: valid x in [t, 256+t)
    uint k0 = (x0 + 0 >= t && x0 + 0 < 256 + t) ? 0xFFFFFFFFu : 0u;
    uint k1 = (x0 + 1 >= t && x0 + 1 < 256 + t) ? 0xFFFFFFFFu : 0u;
    uint k2 = (x0 + 2 >= t && x0 + 2 < 256 + t) ? 0xFFFFFFFFu : 0u;
    uint k3 = (x0 + 3 >= t && x0 + 3 < 256 + t) ? 0xFFFFFFFFu : 0u;

    for (int y = ty; y < 256; y += 4) {   // each wave: 64 rows, sequential
        int yy = y - t;
        vf4 v = {0.f, 0.f, 0.f, 0.f};
        if (yy >= 0 && yy < 256) {        // wave-uniform branch
            const float* __restrict__ row = slice + yy * 256;
            vf4 B = *reinterpret_cast<const vf4*>(row + 4 * m2c);
            float w0, w1, w2, w3;
            if (TR == 0) {
                w0 = B.x; w1 = B.y; w2 = B.z; w3 = B.w;
            } else {
                vf4 A = *reinterpret_cast<const vf4*>(row + 4 * m1c);
                float cc[8] = {A.x, A.y, A.z, A.w, B.x, B.y, B.z, B.w};
                w0 = cc[4 - TR]; w1 = cc[5 - TR];   // compile-time indices
                w2 = cc[6 - TR]; w3 = cc[7 - TR];
            }
            v.x = __uint_as_float(__float_as_uint(w0) & k0);
            v.y = __uint_as_float(__float_as_uint(w1) & k1);
            v.z = __uint_as_float(__float_as_uint(w2) & k2);
            v.w = __uint_as_float(__float_as_uint(w3) & k3);
        }
        __builtin_nontemporal_store(v, reinterpret_cast<vf4*>(oplane + y * 256 + x0));
    }
}

__global__ __launch_bounds__(256) void cost_volume_kernel(
    const float* __restrict__ in, float* __restrict__ out)
{
    int ca = blockIdx.x;                  // 144, fastest -> adjacent blocks
    int d  = blockIdx.y;                  //   write adjacent plane regions
    int c = ca / 9;
    int a = ca - c * 9;
    int t = (d - 4) * (a - 4);            // block-uniform shift

    const float* __restrict__ slice = in + (long)ca * 65536;
    float* __restrict__ oplane = out + ((long)(d * 16 + c) * 9 + a) * 65536L;

    int tx = threadIdx.x;                 // 0..63
    int ty = threadIdx.y;                 // 0..3

    switch (t & 3) {
    case 0: plane_loop<0>(slice, oplane, t, tx, ty); break;
    case 1: plane_loop<1>(slice, oplane, t, tx, ty); break;
    case 2: plane_loop<2>(slice, oplane, t, tx, ty); break;
    case 3: plane_loop<3>(slice, oplane, t, tx, ty); break;
    }
}

extern "C" void kernel_launch(void* const* d_in, const int* in_sizes, int n_in,
                              void* d_out, int out_size, void* d_ws, size_t ws_size,
                              hipStream_t stream)
{
    const float* in = (const float*)d_in[0];
    float* out = (float*)d_out;

    dim3 block(64, 4, 1);    // 256 threads = 4 waves
    dim3 grid(144, 9, 1);    // one block per (ca, d) output plane; 1296 blocks
    cost_volume_kernel<<<grid, block, 0, stream>>>(in, out);
}

// Round 10
// 69.007 us; speedup vs baseline: 1.0752x; 1.0748x over previous
//
#include <hip/hip_runtime.h>

// Output: (1, 9, 16, 9, 256, 256) f32 — out[d][c][a][y][x]
// Input:  (1, 16, 9, 256, 256)  f32 — in[c][a][y][x]
// t = (d-4)*(a-4); out[d][c][a][y][x] = in[c][a][y-t][x-t] if in-bounds else 0.
//
// FINAL (= round-5 optimum, 67.6 us): scatter decomposition — one block owns
// one (c,a) slice x one 16-row INPUT tile (read exactly once into LDS, no
// halo), emits 9 d-shifted copies via uniform funnel-shift of aligned LDS
// chunks, NT dwordx4 stores. RTILE=16 keeps 8 blocks/CU (32 waves/CU) for
// max write parallelism; bx-fastest dispatch makes all 8 XCDs write adjacent
// regions simultaneously. Verified regressions: plain stores (+9us, L2 churn),
// RTILE=32 (+6us, occupancy), XCD-chunked swizzle (+7us), per-plane
// sequential streams (+7us).

#define RTILE 16

typedef float vf4 __attribute__((ext_vector_type(4)));

template<int TR>
__device__ __forceinline__ void emit_plane(const float* __restrict__ lds_t,
                                           float* __restrict__ oplane,
                                           int g0, int t, int tq,
                                           int tx, int ty)
{
    for (int yb = ty; yb < RTILE; yb += 4) {          // wave-uniform row
        int y = g0 + yb + t;
        if (y < 0 || y >= 256) continue;
        const float* __restrict__ lrow = lds_t + yb * 256;
        float* __restrict__ orow = oplane + (long)y * 256;

        int m2 = tx - tq;                 // aligned chunk indices
        int m2c = m2 < 0 ? 0 : (m2 > 63 ? 63 : m2);
        vf4 B = *reinterpret_cast<const vf4*>(lrow + 4 * m2c);
        float w0, w1, w2, w3;
        if (TR == 0) {
            w0 = B.x; w1 = B.y; w2 = B.z; w3 = B.w;
        } else {
            int m1 = m2 - 1;
            int m1c = m1 < 0 ? 0 : (m1 > 63 ? 63 : m1);
            vf4 A = *reinterpret_cast<const vf4*>(lrow + 4 * m1c);
            float cc[8] = {A.x, A.y, A.z, A.w, B.x, B.y, B.z, B.w};
            w0 = cc[4 - TR]; w1 = cc[5 - TR];         // compile-time indices
            w2 = cc[6 - TR]; w3 = cc[7 - TR];
        }
        int x0 = 4 * tx;
        int lo = t, hi = 256 + t;                     // valid x: [t, 256+t)
        vf4 v;
        v.x = (x0 + 0 >= lo && x0 + 0 < hi) ? w0 : 0.f;
        v.y = (x0 + 1 >= lo && x0 + 1 < hi) ? w1 : 0.f;
        v.z = (x0 + 2 >= lo && x0 + 2 < hi) ? w2 : 0.f;
        v.w = (x0 + 3 >= lo && x0 + 3 < hi) ? w3 : 0.f;
        __builtin_nontemporal_store(v, reinterpret_cast<vf4*>(orow + x0));
    }
}

__global__ __launch_bounds__(256) void cost_volume_kernel(
    const float* __restrict__ in, float* __restrict__ out)
{
    __shared__ float lds_t[RTILE * 256];   // 16 KB -> 8 blocks/CU

    int ca = blockIdx.y;                    // c*9 + a
    int c = ca / 9;
    int a = ca - c * 9;
    int a4 = a - 4;
    int g0 = blockIdx.x * RTILE;            // first input row of tile

    int tx = threadIdx.x;                   // 0..63
    int ty = threadIdx.y;                   // 0..3

    // ---- stage 16 input rows, no halo ----
    const float* __restrict__ slice = in + (long)ca * 65536;
    #pragma unroll
    for (int r0 = 0; r0 < RTILE; r0 += 4) {
        int r = r0 + ty;
        *reinterpret_cast<vf4*>(&lds_t[r * 256 + tx * 4]) =
            *reinterpret_cast<const vf4*>(slice + (long)(g0 + r) * 256 + tx * 4);
    }
    __syncthreads();

    // ---- scatter to 9 d-shifted planes ----
    #pragma unroll
    for (int d = 0; d < 9; ++d) {
        int t = (d - 4) * a4;
        float* __restrict__ oplane = out + ((long)(d * 16 + c) * 9 + a) * 65536L;
        int tq = t >> 2;                    // arithmetic shift = floor div
        switch (t & 3) {
        case 0: emit_plane<0>(lds_t, oplane, g0, t, tq, tx, ty); break;
        case 1: emit_plane<1>(lds_t, oplane, g0, t, tq, tx, ty); break;
        case 2: emit_plane<2>(lds_t, oplane, g0, t, tq, tx, ty); break;
        case 3: emit_plane<3>(lds_t, oplane, g0, t, tq, tx, ty); break;
        }

        // ---- distributed zero-fill: block bi fills zero-row bi (if any) ----
        int zn = t < 0 ? -t : t;            // 0..16 uncovered rows per plane
        int z0 = t > 0 ? 0 : 256 + t;
        if (zn && ty == (d & 3) && (int)blockIdx.x < zn) {
            float* __restrict__ orow = oplane + (long)(z0 + (int)blockIdx.x) * 256;
            vf4 z = {0.f, 0.f, 0.f, 0.f};
            __builtin_nontemporal_store(z, reinterpret_cast<vf4*>(orow + tx * 4));
        }
    }
}

extern "C" void kernel_launch(void* const* d_in, const int* in_sizes, int n_in,
                              void* d_out, int out_size, void* d_ws, size_t ws_size,
                              hipStream_t stream)
{
    const float* in = (const float*)d_in[0];
    float* out = (float*)d_out;

    dim3 block(64, 4, 1);    // 256 threads = 4 waves
    dim3 grid(16, 144, 1);   // 16 input y-tiles x (16 c * 9 a)
    cost_volume_kernel<<<grid, block, 0, stream>>>(in, out);
}